// Round 7
// baseline (60.312 us; speedup 1.0000x reference)
//
#include <hip/hip_runtime.h>

// CRF forward (buggy-LSE reference) telescoped into per-token parallel form.
// R7: SINGLE kernel node. Cross-block finalize via coherent-point atomics
// (atomicExch partial -> vmcnt(0) -> relaxed atomicAdd counter), winner block
// re-reads partials with agent-scope atomic loads and reduces in fixed order.
// NO __threadfence (R2 showed agent-release = buffer_wbl2 storm, ~30us).
// Counter is a __device__ global (not poisoned); monotonic, winner test
// (old & 4095)==4095 is valid for any number of calls since 4096 | 2^32.
//
// ws layout: [0] partials [4096] floats.

#define L2E 1.44269504088896340736f
#define LN2 0.69314718055994530942f

__device__ unsigned int g_counter = 0;   // monotonic across calls; +4096/call

// 256 threads = 2 sequences of 128 tokens. Thread <-> token.
__global__ __launch_bounds__(256) void crf_fused_kernel(
    const float* __restrict__ wf,      // [T][8]
    const int*   __restrict__ tc,      // [T]
    const float* __restrict__ trans,   // [8][8] trans[next*8+prev]
    float* __restrict__ partials,      // [nblocks]
    float* __restrict__ out,           // [1]
    int nblocks)
{
    const int local = threadIdx.x;
    const int tok   = blockIdx.x * 256 + local;   // global token index
    const int t     = local & 127;                // position within sequence
    const bool active = (t >= 1) && (t <= 126);   // interior tokens only

    // t2t[a*8+b] = trans[b*8+a] * log2e  (transposed -> row-contiguous per a)
    // et[b*8+a]  = exp(trans[b*8+a])     (row-contiguous per b)
    __shared__ float t2t[64];
    __shared__ float et[64];
    __shared__ float Dlds[7][256];
    __shared__ int   tagLds[256];
    __shared__ float red[8];
    __shared__ unsigned int winner;

    // ---- phase 0: build tables (threads 0..63) ----
    if (local < 64) {
        const int b = local >> 3, a = local & 7;   // local = b*8+a
        float v = trans[local];                    // T[next=b, prev=a]
        float v2 = v * L2E;
        t2t[a * 8 + b] = v2;
        et[local] = __builtin_amdgcn_exp2f(v2);    // exp(T[b,a])
    }

    // unconditional coalesced loads (every tok is a valid address)
    const float4* wf4 = reinterpret_cast<const float4*>(wf) + (size_t)tok * 2;
    float4 x = wf4[0];
    float4 y = wf4[1];
    const float f[8] = {x.x, x.y, x.z, x.w, y.x, y.y, y.z, y.w};
    const int tag = tc[tok];

    __syncthreads();   // tables ready

    const float4* t2t4 = reinterpret_cast<const float4*>(t2t);
    const float4* et4  = reinterpret_cast<const float4*>(et);

    float va[8];   // per row a: payload-at-argmax (base-2 units)
    if (active) {
        // v0[b] = (feat[b] + T[b,0]) * log2e  as one fma ; row a=0 of t2t
        float v0[8];
        {
            float4 ta = t2t4[0], tb = t2t4[1];
            const float tr0[8] = {ta.x, ta.y, ta.z, ta.w, tb.x, tb.y, tb.z, tb.w};
            #pragma unroll
            for (int b = 0; b < 8; ++b) v0[b] = fmaf(f[b], L2E, tr0[b]);
        }

        // row 0: keys == payloads -> payload at argmax is the max
        va[0] = fmaxf(fmaxf(fmaxf(fmaxf(v0[0], v0[1]), v0[2]),
                            fmaxf(fmaxf(v0[3], v0[4]), v0[5])),
                      fmaxf(v0[6], v0[7]));

        #pragma unroll
        for (int a = 1; a < 8; ++a) {
            float4 ta = t2t4[a * 2], tb = t2t4[a * 2 + 1];
            const float tra[8] = {ta.x, ta.y, ta.z, ta.w, tb.x, tb.y, tb.z, tb.w};
            float h[8];
            #pragma unroll
            for (int b = 0; b < 8; ++b) h[b] = fmaf(f[b], L2E, tra[b]);
            float hm = fmaxf(fmaxf(fmaxf(fmaxf(h[0], h[1]), h[2]),
                                   fmaxf(fmaxf(h[3], h[4]), h[5])),
                             fmaxf(h[6], h[7]));
            float vb = v0[7];
            #pragma unroll
            for (int b = 6; b >= 0; --b) vb = (h[b] == hm) ? v0[b] : vb;  // first-argmax
            va[a] = vb;
        }
    }

    // publish D_a = va[a] - va[0] for the next token; START (t==0) publishes 0
    if (t == 0) {
        #pragma unroll
        for (int a = 1; a < 8; ++a) Dlds[a - 1][local] = 0.0f;
    } else if (active) {
        #pragma unroll
        for (int a = 1; a < 8; ++a) Dlds[a - 1][local] = va[a] - va[0];
    }
    tagLds[local] = tag;
    __syncthreads();

    float c = 0.0f;
    if (active) {
        float Dp[7];
        #pragma unroll
        for (int a = 0; a < 7; ++a) Dp[a] = Dlds[a][local - 1];

        float f2[8], ef[8];
        #pragma unroll
        for (int b = 0; b < 8; ++b) {
            f2[b] = f[b] * L2E;
            ef[b] = __builtin_amdgcn_exp2f(f2[b]);   // = exp(feat[b])
        }

        // R[a] = sum_b exp(feat[b]) * exp(T[b,a])
        float R[8] = {0, 0, 0, 0, 0, 0, 0, 0};
        #pragma unroll
        for (int b = 0; b < 8; ++b) {
            float4 ea = et4[b * 2], eb = et4[b * 2 + 1];
            const float erow[8] = {ea.x, ea.y, ea.z, ea.w, eb.x, eb.y, eb.z, eb.w};
            const float efb = ef[b];
            #pragma unroll
            for (int a = 0; a < 8; ++a) R[a] = fmaf(efb, erow[a], R[a]);
        }

        // S = sum_a exp2(Dp_a - va_a) * R[a];  Dp_0 = 0 implied
        float S = __builtin_amdgcn_exp2f(-va[0]) * R[0];
        #pragma unroll
        for (int a = 1; a < 8; ++a)
            S += __builtin_amdgcn_exp2f(Dp[a - 1] - va[a]) * R[a];

        c = va[0] + __builtin_amdgcn_logf(S);   // log2; scaled by ln2 at the end

        // last interior token: exact logsumexp over D(126) (final STOP lse), base-2
        if (t == 126) {
            float D[8];
            D[0] = 0.0f;
            #pragma unroll
            for (int a = 1; a < 8; ++a) D[a] = va[a] - va[0];
            float m = fmaxf(fmaxf(fmaxf(fmaxf(D[0], D[1]), D[2]),
                                  fmaxf(fmaxf(D[3], D[4]), D[5])),
                            fmaxf(D[6], D[7]));
            float s2 = 0.0f;
            #pragma unroll
            for (int a = 0; a < 8; ++a) s2 += __builtin_amdgcn_exp2f(D[a] - m);
            c += m + __builtin_amdgcn_logf(s2);
        }

        // truth path (subtracted), base-2 units. tag in [0,6) for interior
        // tokens -> select emit from registers. At t==126 the T[7,tag] term
        // cancels with the STOP step's -T[7,tag_prev].
        float emit = f2[0];
        #pragma unroll
        for (int b = 1; b < 6; ++b) emit = (tag == b) ? f2[b] : emit;
        float tr = 0.0f;
        if (t < 126) {
            int tagn = tagLds[local + 1];
            tr = t2t[tag * 8 + tagn];     // trans[tagn*8+tag] * log2e
        }
        c -= emit + tr;
    }

    // ---- block reduction ----
    #pragma unroll
    for (int off = 32; off >= 1; off >>= 1) c += __shfl_xor(c, off, 64);
    if ((local & 63) == 0) red[local >> 6] = c;
    __syncthreads();

    // ---- publish partial at coherent point, then count-in (no fences) ----
    if (local == 0) {
        float bs = red[0] + red[1] + red[2] + red[3];
        atomicExch(&partials[blockIdx.x], bs);           // RMW -> coherent point
        asm volatile("s_waitcnt vmcnt(0)" ::: "memory"); // order exch before add
        unsigned int old = atomicAdd(&g_counter, 1u);
        winner = ((old & 4095u) == 4095u) ? 1u : 0u;
    }
    __syncthreads();

    // ---- winner block: deterministic fixed-order reduce of all partials ----
    if (winner) {
        float s = 0.0f;
        const int iters = nblocks >> 8;                  // 4096/256 = 16
        for (int k = 0; k < iters; ++k) {
            // agent-scope atomic load: bypasses (possibly stale) local L1/L2
            s += __hip_atomic_load(&partials[local + (k << 8)],
                                   __ATOMIC_RELAXED, __HIP_MEMORY_SCOPE_AGENT);
        }
        #pragma unroll
        for (int off = 32; off >= 1; off >>= 1) s += __shfl_xor(s, off, 64);
        if ((local & 63) == 0) red[4 + (local >> 6)] = s;
        __syncthreads();
        if (local == 0)
            out[0] = (red[4] + red[5] + red[6] + red[7]) * LN2;
    }
}

extern "C" void kernel_launch(void* const* d_in, const int* in_sizes, int n_in,
                              void* d_out, int out_size, void* d_ws, size_t ws_size,
                              hipStream_t stream) {
    const float* wf    = (const float*)d_in[0];
    const int*   tc    = (const int*)d_in[2];
    const float* trans = (const float*)d_in[3];

    const int T = in_sizes[1];          // 8192 * 128 = 1048576 tokens
    const int nblocks = T / 256;        // 4096 (multiple of 256)

    float* partials = (float*)d_ws;     // nblocks floats

    crf_fused_kernel<<<nblocks, 256, 0, stream>>>(wf, tc, trans, partials,
                                                  (float*)d_out, nblocks);
}

// Round 8
// 31.499 us; speedup vs baseline: 1.9147x; 1.9147x over previous
//
#include <hip/hip_runtime.h>

// CRF forward (buggy-LSE reference) telescoped into per-token parallel form.
// R8: one sequence per WAVE (lane owns tokens lane and lane+64). Predecessor-D
// exchange via in-wave shuffles -> no barriers / no LDS for the exchange.
// Tables built redundantly per wave (identical-value LDS writes, no barrier).
// 2 dispatches (R7 proved single-node finalize costs ~40us in device atomics).
//
// ws layout: [0] partials [4096] floats.

#define L2E 1.44269504088896340736f
#define LN2 0.69314718055994530942f

// payload-at-argmax per row a over b of h[b]=f[b]*L2E+t2t[a][b]; payload v0[b].
__device__ __forceinline__ void compute_va(const float f[8],
                                           const float4* __restrict__ t2t4,
                                           float va[8]) {
    float v0[8];
    {
        float4 ta = t2t4[0], tb = t2t4[1];
        const float tr0[8] = {ta.x, ta.y, ta.z, ta.w, tb.x, tb.y, tb.z, tb.w};
        #pragma unroll
        for (int b = 0; b < 8; ++b) v0[b] = fmaf(f[b], L2E, tr0[b]);
    }
    va[0] = fmaxf(fmaxf(fmaxf(fmaxf(v0[0], v0[1]), v0[2]),
                        fmaxf(fmaxf(v0[3], v0[4]), v0[5])),
                  fmaxf(v0[6], v0[7]));
    #pragma unroll
    for (int a = 1; a < 8; ++a) {
        float4 ta = t2t4[a * 2], tb = t2t4[a * 2 + 1];
        const float tra[8] = {ta.x, ta.y, ta.z, ta.w, tb.x, tb.y, tb.z, tb.w};
        float h[8];
        #pragma unroll
        for (int b = 0; b < 8; ++b) h[b] = fmaf(f[b], L2E, tra[b]);
        float hm = fmaxf(fmaxf(fmaxf(fmaxf(h[0], h[1]), h[2]),
                               fmaxf(fmaxf(h[3], h[4]), h[5])),
                         fmaxf(h[6], h[7]));
        float vb = v0[7];
        #pragma unroll
        for (int b = 6; b >= 0; --b) vb = (h[b] == hm) ? v0[b] : vb;  // first-argmax
        va[a] = vb;
    }
}

// c = va[0] + log2(S), S = exp2(-va0)*R0 + sum_{a>=1} exp2(Dp[a-1]-va[a])*R[a]
__device__ __forceinline__ float token_core(const float f[8], const float va[8],
                                            const float Dp[7],
                                            const float4* __restrict__ et4) {
    float ef[8];
    #pragma unroll
    for (int b = 0; b < 8; ++b) ef[b] = __builtin_amdgcn_exp2f(f[b] * L2E);
    float R[8] = {0, 0, 0, 0, 0, 0, 0, 0};
    #pragma unroll
    for (int b = 0; b < 8; ++b) {
        float4 ea = et4[b * 2], eb = et4[b * 2 + 1];
        const float erow[8] = {ea.x, ea.y, ea.z, ea.w, eb.x, eb.y, eb.z, eb.w};
        const float efb = ef[b];
        #pragma unroll
        for (int a = 0; a < 8; ++a) R[a] = fmaf(efb, erow[a], R[a]);
    }
    float S = __builtin_amdgcn_exp2f(-va[0]) * R[0];
    #pragma unroll
    for (int a = 1; a < 8; ++a)
        S += __builtin_amdgcn_exp2f(Dp[a - 1] - va[a]) * R[a];
    return va[0] + __builtin_amdgcn_logf(S);
}

__device__ __forceinline__ float emit_sel(const float f[8], int tag) {
    float e = f[0];
    #pragma unroll
    for (int b = 1; b < 6; ++b) e = (tag == b) ? f[b] : e;
    return e * L2E;
}

// 128 threads = 2 waves; wave w handles sequence blockIdx*2+w.
// Lane owns tokens tA = seq*128+lane (t=lane) and tB = tA+64 (t=lane+64).
__global__ __launch_bounds__(128) void crf_main_kernel(
    const float* __restrict__ wf,      // [T][8]
    const int*   __restrict__ tc,      // [T]
    const float* __restrict__ trans,   // [8][8] trans[next*8+prev]
    float* __restrict__ partials)      // [gridDim.x]
{
    const int local = threadIdx.x;
    const int lane  = local & 63;
    const int wave  = local >> 6;
    const int tokA  = (blockIdx.x * 2 + wave) * 128 + lane;  // t = lane
    const int tokB  = tokA + 64;                             // t = lane+64

    // t2t[a*8+b] = trans[b*8+a]*log2e ; et[b*8+a] = exp(trans[b*8+a])
    __shared__ float t2t[64];
    __shared__ float et[64];
    __shared__ float red[2];

    // ---- tables: each wave builds ALL 64 entries (identical-value writes
    // from the two waves are benign; wave reads its own writes, no barrier) ----
    {
        const int b = lane >> 3, a = lane & 7;     // lane = b*8+a
        float v2 = trans[lane] * L2E;              // T[next=b, prev=a]*log2e
        t2t[a * 8 + b] = v2;
        et[lane] = __builtin_amdgcn_exp2f(v2);     // exp(T[b,a])
    }

    // ---- per-token loads (all coalesced within the wave) ----
    const float4* wf4 = reinterpret_cast<const float4*>(wf);
    float4 xa = wf4[(size_t)tokA * 2], ya = wf4[(size_t)tokA * 2 + 1];
    float4 xb = wf4[(size_t)tokB * 2], yb = wf4[(size_t)tokB * 2 + 1];
    const float fA[8] = {xa.x, xa.y, xa.z, xa.w, ya.x, ya.y, ya.z, ya.w};
    const float fB[8] = {xb.x, xb.y, xb.z, xb.w, yb.x, yb.y, yb.z, yb.w};
    const int tagA = tc[tokA], tagB = tc[tokB];

    // tag of successor token: rotate-down shuffle (lane L <- L+1, 63 <- 0)
    const int rotl = (lane + 1) & 63;
    const int tnA0 = __shfl(tagA, rotl, 64);
    const int tnB0 = __shfl(tagB, rotl, 64);
    const int tagnA = (lane == 63) ? tnB0 : tnA0;  // succ of t=63 is t=64 (B@0)
    const int tagnB = tnB0;                        // lane 63 (t=127) unused

    const float4* t2t4 = reinterpret_cast<const float4*>(t2t);
    const float4* et4  = reinterpret_cast<const float4*>(et);

    float vaA[8], vaB[8];
    compute_va(fA, t2t4, vaA);   // lane 0 (START) -> garbage, masked later
    compute_va(fB, t2t4, vaB);

    // ---- predecessor-D exchange, all in-wave ----
    // DA[a-1] = D_a of token t=lane   (forced 0 at lane 0 = START)
    // DB[a-1] = D_a of token t=lane+64
    float DpA[7], DpB[7];
    #pragma unroll
    for (int a = 0; a < 7; ++a) {
        float DA = (lane == 0) ? 0.0f : vaA[a + 1] - vaA[0];
        float DB = vaB[a + 1] - vaB[0];
        float upA = __shfl_up(DA, 1, 64);   // lane L <- L-1 (lane0: own, unused)
        float upB = __shfl_up(DB, 1, 64);
        float bc63 = __shfl(DA, 63, 64);    // D of t=63, pred of t=64
        DpA[a] = upA;
        DpB[a] = (lane == 0) ? bc63 : upB;
    }

    // ---- token A: t = lane in [0,63]; active iff lane>=1; never t==126 ----
    float cA = token_core(fA, vaA, DpA, et4);
    cA -= emit_sel(fA, tagA) + t2t[tagA * 8 + tagnA];   // t<126 always
    // ---- token B: t = lane+64; active iff lane<=62; t==126 at lane 62 ----
    float cB = token_core(fB, vaB, DpB, et4);
    if (lane == 62) {  // final STOP logsumexp over D(126), base-2
        float D[8];
        D[0] = 0.0f;
        #pragma unroll
        for (int a = 1; a < 8; ++a) D[a] = vaB[a] - vaB[0];
        float m = fmaxf(fmaxf(fmaxf(fmaxf(D[0], D[1]), D[2]),
                              fmaxf(fmaxf(D[3], D[4]), D[5])),
                        fmaxf(D[6], D[7]));
        float s2 = 0.0f;
        #pragma unroll
        for (int a = 0; a < 8; ++a) s2 += __builtin_amdgcn_exp2f(D[a] - m);
        cB += m + __builtin_amdgcn_logf(s2);
    }
    float trB = (lane == 62) ? 0.0f : t2t[tagB * 8 + tagnB];  // cancels at t=126
    cB -= emit_sel(fB, tagB) + trB;

    float c = ((lane >= 1) ? cA : 0.0f) + ((lane <= 62) ? cB : 0.0f);

    // ---- wave reduce + 2-wave combine ----
    #pragma unroll
    for (int off = 32; off >= 1; off >>= 1) c += __shfl_xor(c, off, 64);
    if (lane == 0) red[wave] = c;
    __syncthreads();
    if (local == 0) partials[blockIdx.x] = red[0] + red[1];
}

// 1024 threads; n == 4096 -> one float4 per thread. Final scale by ln2.
__global__ __launch_bounds__(1024) void reduce_kernel(
    const float* __restrict__ partials, int n, float* __restrict__ out)
{
    __shared__ float red[16];
    float s = 0.0f;
    for (int i = threadIdx.x; i * 4 < n; i += 1024) {
        float4 p = reinterpret_cast<const float4*>(partials)[i];
        s += (p.x + p.y) + (p.z + p.w);
    }
    #pragma unroll
    for (int off = 32; off >= 1; off >>= 1) s += __shfl_xor(s, off, 64);
    if ((threadIdx.x & 63) == 0) red[threadIdx.x >> 6] = s;
    __syncthreads();
    if (threadIdx.x == 0) {
        float tot = 0.0f;
        #pragma unroll
        for (int w = 0; w < 16; ++w) tot += red[w];
        out[0] = tot * LN2;
    }
}

extern "C" void kernel_launch(void* const* d_in, const int* in_sizes, int n_in,
                              void* d_out, int out_size, void* d_ws, size_t ws_size,
                              hipStream_t stream) {
    const float* wf    = (const float*)d_in[0];
    const int*   tc    = (const int*)d_in[2];
    const float* trans = (const float*)d_in[3];

    const int T = in_sizes[1];          // 8192 * 128 = 1048576 tokens
    const int nblocks = T / 256;        // 4096 blocks (2 sequences each)

    float* partials = (float*)d_ws;     // nblocks floats

    crf_main_kernel<<<nblocks, 128, 0, stream>>>(wf, tc, trans, partials);
    reduce_kernel<<<1, 1024, 0, stream>>>(partials, nblocks, (float*)d_out);
}

// Round 9
// 19.133 us; speedup vs baseline: 3.1523x; 1.6463x over previous
//
#include <hip/hip_runtime.h>

// CRF forward (buggy-LSE reference) telescoped into per-token parallel form.
// R9: R6 frame (1 tok/thread, 4096x256, 2 nodes) with:
//  - t2t LDS table REMOVED: argmax/payload in natural domain using direct
//    trans[] accesses (compile-time indices -> wave-uniform s_load, SGPR
//    operands in v_add). No LDS reads, no VGPR address math for the table.
//  - single barrier: et build + Dlds/tagLds publish all precede it.
//  - base-2 conversion applied once per row (15 muls), exp2/log2 as before.
//
// ws layout: [0] partials [4096] floats.

#define L2E 1.44269504088896340736f
#define LN2 0.69314718055994530942f

// 256 threads = 2 sequences of 128 tokens. Thread <-> token.
__global__ __launch_bounds__(256) void crf_main_kernel(
    const float* __restrict__ wf,      // [T][8]
    const int*   __restrict__ tc,      // [T]
    const float* __restrict__ trans,   // [8][8] trans[next*8+prev]
    float* __restrict__ partials)      // [gridDim.x]
{
    const int local = threadIdx.x;
    const int tok   = blockIdx.x * 256 + local;   // global token index
    const int t     = local & 127;                // position within sequence
    const bool active = (t >= 1) && (t <= 126);   // interior tokens only

    __shared__ float et[64];       // et[b*8+a] = exp(trans[b*8+a])
    __shared__ float Dlds[7][256]; // D2_a of token t, read by token t+1
    __shared__ int   tagLds[256];
    __shared__ float red[4];

    // ---- et build (threads 0..63); visible after the single barrier ----
    if (local < 64) {
        float v = trans[local];                       // vector load, coalesced
        et[local] = __builtin_amdgcn_exp2f(v * L2E);  // exp(T[b,a])
    }

    // ---- unconditional coalesced loads ----
    const float4* wf4 = reinterpret_cast<const float4*>(wf) + (size_t)tok * 2;
    float4 x = wf4[0];
    float4 y = wf4[1];
    const float f[8] = {x.x, x.y, x.z, x.w, y.x, y.y, y.z, y.w};
    const int tag = tc[tok];

    // ---- va in NATURAL domain: pure adds with SGPR trans operands ----
    float va2[8];   // va * log2e (converted after argmax)
    if (active) {
        float v0[8];
        #pragma unroll
        for (int b = 0; b < 8; ++b) v0[b] = f[b] + trans[b * 8];

        // row 0: keys == payloads -> payload at argmax is the max
        float va0 = fmaxf(fmaxf(fmaxf(fmaxf(v0[0], v0[1]), v0[2]),
                                fmaxf(fmaxf(v0[3], v0[4]), v0[5])),
                          fmaxf(v0[6], v0[7]));
        va2[0] = va0 * L2E;

        #pragma unroll
        for (int a = 1; a < 8; ++a) {
            float h[8];
            #pragma unroll
            for (int b = 0; b < 8; ++b) h[b] = f[b] + trans[b * 8 + a];
            float hm = fmaxf(fmaxf(fmaxf(fmaxf(h[0], h[1]), h[2]),
                                   fmaxf(fmaxf(h[3], h[4]), h[5])),
                             fmaxf(h[6], h[7]));
            float vb = v0[7];
            #pragma unroll
            for (int b = 6; b >= 0; --b) vb = (h[b] == hm) ? v0[b] : vb;  // first-argmax
            va2[a] = vb * L2E;
        }
    }

    // publish D2_a = va2[a] - va2[0]; START (t==0) publishes 0
    if (t == 0) {
        #pragma unroll
        for (int a = 1; a < 8; ++a) Dlds[a - 1][local] = 0.0f;
    } else if (active) {
        #pragma unroll
        for (int a = 1; a < 8; ++a) Dlds[a - 1][local] = va2[a] - va2[0];
    }
    tagLds[local] = tag;

    __syncthreads();   // single barrier: et + Dlds + tagLds all ready

    const float4* et4 = reinterpret_cast<const float4*>(et);

    float c = 0.0f;
    if (active) {
        float Dp[7];
        #pragma unroll
        for (int a = 0; a < 7; ++a) Dp[a] = Dlds[a][local - 1];

        float ef[8];
        #pragma unroll
        for (int b = 0; b < 8; ++b)
            ef[b] = __builtin_amdgcn_exp2f(f[b] * L2E);   // = exp(feat[b])

        // R[a] = sum_b exp(feat[b]) * exp(T[b,a])
        float R[8] = {0, 0, 0, 0, 0, 0, 0, 0};
        #pragma unroll
        for (int b = 0; b < 8; ++b) {
            float4 ea = et4[b * 2], eb = et4[b * 2 + 1];
            const float erow[8] = {ea.x, ea.y, ea.z, ea.w, eb.x, eb.y, eb.z, eb.w};
            const float efb = ef[b];
            #pragma unroll
            for (int a = 0; a < 8; ++a) R[a] = fmaf(efb, erow[a], R[a]);
        }

        // S = sum_a exp2(Dp_a - va2_a) * R[a];  Dp_0 = 0 implied
        float S = __builtin_amdgcn_exp2f(-va2[0]) * R[0];
        #pragma unroll
        for (int a = 1; a < 8; ++a)
            S += __builtin_amdgcn_exp2f(Dp[a - 1] - va2[a]) * R[a];

        c = va2[0] + __builtin_amdgcn_logf(S);   // log2 units; xLN2 at the end

        // last interior token: exact logsumexp over D2(126) (final STOP lse)
        if (t == 126) {
            float D[8];
            D[0] = 0.0f;
            #pragma unroll
            for (int a = 1; a < 8; ++a) D[a] = va2[a] - va2[0];
            float m = fmaxf(fmaxf(fmaxf(fmaxf(D[0], D[1]), D[2]),
                                  fmaxf(fmaxf(D[3], D[4]), D[5])),
                            fmaxf(D[6], D[7]));
            float s2 = 0.0f;
            #pragma unroll
            for (int a = 0; a < 8; ++a) s2 += __builtin_amdgcn_exp2f(D[a] - m);
            c += m + __builtin_amdgcn_logf(s2);
        }

        // truth path (subtracted), converted to log2 units. tag in [0,6) for
        // interior tokens -> emit from registers. At t==126 the T[7,tag] term
        // cancels with the STOP step's -T[7,tag_prev].
        float emit = f[0];
        #pragma unroll
        for (int b = 1; b < 6; ++b) emit = (tag == b) ? f[b] : emit;
        float sub = emit * L2E;
        if (t < 126) {
            int tagn = tagLds[local + 1];
            float tr = trans[tagn * 8 + tag];   // runtime index -> vector gather
            sub = fmaf(tr, L2E, sub);
        }
        c -= sub;
    }

    // ---- block reduction ----
    #pragma unroll
    for (int off = 32; off >= 1; off >>= 1) c += __shfl_xor(c, off, 64);
    if ((local & 63) == 0) red[local >> 6] = c;
    __syncthreads();
    if (local == 0) partials[blockIdx.x] = red[0] + red[1] + red[2] + red[3];
}

// 1024 threads; n == 4096 -> one float4 per thread. Final scale by ln2.
__global__ __launch_bounds__(1024) void reduce_kernel(
    const float* __restrict__ partials, int n, float* __restrict__ out)
{
    __shared__ float red[16];
    float s = 0.0f;
    for (int i = threadIdx.x; i * 4 < n; i += 1024) {
        float4 p = reinterpret_cast<const float4*>(partials)[i];
        s += (p.x + p.y) + (p.z + p.w);
    }
    #pragma unroll
    for (int off = 32; off >= 1; off >>= 1) s += __shfl_xor(s, off, 64);
    if ((threadIdx.x & 63) == 0) red[threadIdx.x >> 6] = s;
    __syncthreads();
    if (threadIdx.x == 0) {
        float tot = 0.0f;
        #pragma unroll
        for (int w = 0; w < 16; ++w) tot += red[w];
        out[0] = tot * LN2;
    }
}

extern "C" void kernel_launch(void* const* d_in, const int* in_sizes, int n_in,
                              void* d_out, int out_size, void* d_ws, size_t ws_size,
                              hipStream_t stream) {
    const float* wf    = (const float*)d_in[0];
    const int*   tc    = (const int*)d_in[2];
    const float* trans = (const float*)d_in[3];

    const int T = in_sizes[1];          // 8192 * 128 = 1048576 tokens
    const int nblocks = T / 256;        // 4096

    float* partials = (float*)d_ws;     // nblocks floats

    crf_main_kernel<<<nblocks, 256, 0, stream>>>(wf, tc, trans, partials);
    reduce_kernel<<<1, 1024, 0, stream>>>(partials, nblocks, (float*)d_out);
}